// Round 12
// baseline (546.311 us; speedup 1.0000x reference)
//
#include <hip/hip_runtime.h>
#include <stdint.h>
#include <math.h>

typedef unsigned short u16;
typedef __attribute__((ext_vector_type(4))) float f32x4;
typedef __attribute__((ext_vector_type(8))) short s16x8;
typedef __attribute__((ext_vector_type(4))) int i32x4;

#define U_N 8192
#define E_N 200000
#define M_PAD 200064   // 1563 * 128
#define NMT 1563
#define D_N 768
#define DE_N 50
#define KP_E 832       // 13 * 64
#define NTI 13
#define BN_EPS 1e-5f

__device__ __forceinline__ u16 f2bf(float f) {
  union { float f; unsigned u; } v; v.f = f;
  return (u16)((v.u + 0x7fffu + ((v.u >> 16) & 1u)) >> 16);
}
__device__ __forceinline__ float bf2f(u16 v) {
  union { unsigned u; float f; } x; x.u = ((unsigned)v) << 16; return x.f;
}
__device__ __forceinline__ void gload16(const void* g, void* l) {
  __builtin_amdgcn_global_load_lds((const __attribute__((address_space(1))) void*)g,
                                   (__attribute__((address_space(3))) void*)l, 16, 0, 0);
}

// ---------------- searchsorted + histogram (merged) ----------------
__global__ void k_lh(const int* __restrict__ uniq, const int* __restrict__ src,
                     int* __restrict__ lidx, int* __restrict__ counts) {
  int e = blockIdx.x * 256 + threadIdx.x;
  if (e >= E_N) return;
  int v = src[e];
  int lo = 0, hi = U_N;
  while (lo < hi) { int mid = (lo + hi) >> 1; if (uniq[mid] < v) lo = mid + 1; else hi = mid; }
  lidx[e] = lo;
  atomicAdd(&counts[lo], 1);
}

__global__ void k_scan(const int* __restrict__ counts, int* __restrict__ starts) {
  __shared__ int part[1024];
  const int t = threadIdx.x;
  const int base = t * 8;
  int loc[8]; int s = 0;
#pragma unroll
  for (int i = 0; i < 8; i++) { loc[i] = s; s += counts[base + i]; }
  part[t] = s; __syncthreads();
  for (int off = 1; off < 1024; off <<= 1) {
    int v = (t >= off) ? part[t - off] : 0;
    __syncthreads();
    part[t] += v;
    __syncthreads();
  }
  const int pre = (t == 0) ? 0 : part[t - 1];
#pragma unroll
  for (int i = 0; i < 8; i++) starts[base + i] = pre + loc[i];
  if (t == 1023) starts[8192] = pre + s;
}

__global__ void k_scatter(const int* __restrict__ lidx, const int* __restrict__ starts,
                          int* __restrict__ cursor, int* __restrict__ eord,
                          int* __restrict__ nsort) {
  int e = blockIdx.x * 256 + threadIdx.x;
  if (e >= E_N) return;
  int u = lidx[e];
  int pos = atomicAdd(&cursor[u], 1);
  eord[starts[u] + pos] = e;
  nsort[starts[u] + pos] = u;
}

// ------- pack+quantize A (sorted order): Aq[pos][k] int8 (K=832), per-row amax -------
__global__ __launch_bounds__(256)
void k_pack_q8(const float* __restrict__ tgt, const float* __restrict__ edg,
               const int* __restrict__ eord, char* __restrict__ Aq,
               float* __restrict__ sA) {
  const int row = blockIdx.x * 4 + (threadIdx.x >> 6);
  const int lane = threadIdx.x & 63;
  if (row >= E_N) return;
  const int e = eord[row];
  const int k0 = lane * 16;
  float v[16];
#pragma unroll
  for (int z = 0; z < 16; z++) v[z] = 0.f;
  if (k0 < D_N) {
    const f32x4* p = (const f32x4*)(tgt + (size_t)e * D_N + k0);
#pragma unroll
    for (int zz = 0; zz < 4; zz++) {
      const f32x4 f = p[zz];
#pragma unroll
      for (int b = 0; b < 4; b++) v[zz * 4 + b] = f[b];
    }
  } else if (k0 < KP_E) {
#pragma unroll
    for (int z = 0; z < 16; z++) {
      const int kk = k0 + z - D_N;
      v[z] = (kk < DE_N) ? edg[(size_t)e * DE_N + kk] : 0.f;
    }
  }
  float am = 0.f;
#pragma unroll
  for (int z = 0; z < 16; z++) am = fmaxf(am, fabsf(v[z]));
#pragma unroll
  for (int off = 32; off > 0; off >>= 1) am = fmaxf(am, __shfl_xor(am, off));
  am = fmaxf(am, 1e-8f);
  const float inv = 127.f / am;
  if (lane == 0) sA[row] = am / 127.f;
  if (k0 < KP_E) {
    int wq[4];
#pragma unroll
    for (int zz = 0; zz < 4; zz++) {
      int b0 = (int)rintf(fminf(fmaxf(v[zz*4+0] * inv, -127.f), 127.f));
      int b1 = (int)rintf(fminf(fmaxf(v[zz*4+1] * inv, -127.f), 127.f));
      int b2 = (int)rintf(fminf(fmaxf(v[zz*4+2] * inv, -127.f), 127.f));
      int b3 = (int)rintf(fminf(fmaxf(v[zz*4+3] * inv, -127.f), 127.f));
      wq[zz] = (b0 & 255) | ((b1 & 255) << 8) | ((b2 & 255) << 16) | (b3 << 24);
    }
    i32x4 out = {wq[0], wq[1], wq[2], wq[3]};
    *(i32x4*)(Aq + (size_t)row * KP_E + k0) = out;
  }
}

// ------- quantize W_edge rows (818 -> 832 pad), per-row amax -------
__global__ __launch_bounds__(256)
void k_convw_q8(const float* __restrict__ W, char* __restrict__ Wq,
                float* __restrict__ sW) {
  const int row = blockIdx.x * 4 + (threadIdx.x >> 6);
  const int lane = threadIdx.x & 63;
  if (row >= D_N) return;
  const int k0 = lane * 16;
  float v[16];
#pragma unroll
  for (int z = 0; z < 16; z++) v[z] = 0.f;
  if (k0 < KP_E) {
#pragma unroll
    for (int z = 0; z < 16; z++) {
      const int kk = k0 + z;
      v[z] = (kk < D_N + DE_N) ? W[(size_t)row * (D_N + DE_N) + kk] : 0.f;
    }
  }
  float am = 0.f;
#pragma unroll
  for (int z = 0; z < 16; z++) am = fmaxf(am, fabsf(v[z]));
#pragma unroll
  for (int off = 32; off > 0; off >>= 1) am = fmaxf(am, __shfl_xor(am, off));
  am = fmaxf(am, 1e-8f);
  const float inv = 127.f / am;
  if (lane == 0) sW[row] = am / 127.f;
  if (k0 < KP_E) {
    int wq[4];
#pragma unroll
    for (int zz = 0; zz < 4; zz++) {
      int b0 = (int)rintf(fminf(fmaxf(v[zz*4+0] * inv, -127.f), 127.f));
      int b1 = (int)rintf(fminf(fmaxf(v[zz*4+1] * inv, -127.f), 127.f));
      int b2 = (int)rintf(fminf(fmaxf(v[zz*4+2] * inv, -127.f), 127.f));
      int b3 = (int)rintf(fminf(fmaxf(v[zz*4+3] * inv, -127.f), 127.f));
      wq[zz] = (b0 & 255) | ((b1 & 255) << 8) | ((b2 & 255) << 16) | (b3 << 24);
    }
    i32x4 out = {wq[0], wq[1], wq[2], wq[3]};
    *(i32x4*)(Wq + (size_t)row * KP_E + k0) = out;
  }
}

// ---------------- merged bf16 weight conversion (W1 + W2) ----------------
__global__ void k_conv_w2(const float* __restrict__ W1, const float* __restrict__ W2,
                          u16* __restrict__ w1b, u16* __restrict__ w2b) {
  int i = blockIdx.x * 256 + threadIdx.x;
  const int C = D_N * D_N;
  if (i < C) w1b[i] = f2bf(W1[i]);
  else if (i < 2 * C) w2b[i - C] = f2bf(W2[i - C]);
}

// ====== edge GEMM v12: int8, 128x128, 4 waves, ring-2 BK=64, 4 blocks/CU ======
// B (weights, 638 KB, L2-resident) loaded global->VGPR directly — NO LDS round-trip.
// LDS carries A only: per-tile LDS traffic 48KB -> 24KB/block => MFMA-bound (theory).
// A swizzle (proven): LDS slot p of row r holds global slot p ^ ((r>>1)&3).
__global__ __launch_bounds__(256, 4)
void gemm_edge12(const char* __restrict__ Aq, const char* __restrict__ Wq,
                 const float* __restrict__ sA, const float* __restrict__ sW,
                 const float* __restrict__ bias, const int* __restrict__ nsort,
                 float* __restrict__ agg) {
  // ring buf b at b*8192 (b=0..1): A [128][64B]. Epilogue: u16 tile[128][132] at 0
  // (33792 B); nseg at 33792; sAl at 34304.
  __shared__ char lds[34816];

  // bijective XCD swizzle, nwg = 9378 = 8*1172 + 2
  const int orig = blockIdx.x;
  const int xcd = orig & 7, i8_ = orig >> 3;
  const int wgid = (xcd < 2 ? xcd * 1173 : 2346 + (xcd - 2) * 1172) + i8_;
  const int bm = (wgid / 6) * 128;
  const int bn = (wgid % 6) * 128;

  const int tid = threadIdx.x;
  const int w = tid >> 6, lane = tid & 63;
  const int wm = w & 1, wn = w >> 1;          // wave tile: rows wm*64, cols wn*64
  const int rl = lane & 15, K16 = lane >> 4;
  const int sws = (K16 ^ ((rl >> 1) & 3)) * 16;
  const int srow = tid >> 2;
  const int sg0 = (tid & 3) ^ ((srow >> 1) & 3);

  // B fragment byte offsets into Wq (fragment layout == MFMA layout, no swizzle)
  const unsigned bo0 = (unsigned)(bn + wn * 64 + 0 * 16 + rl) * KP_E + K16 * 16;
  const unsigned bo1 = (unsigned)(bn + wn * 64 + 1 * 16 + rl) * KP_E + K16 * 16;
  const unsigned bo2 = (unsigned)(bn + wn * 64 + 2 * 16 + rl) * KP_E + K16 * 16;
  const unsigned bo3 = (unsigned)(bn + wn * 64 + 3 * 16 + rl) * KP_E + K16 * 16;

  i32x4 acc[4][4] = {};
  i32x4 bX[4], bY[4];   // double-buffered B fragment sets (literal indices only)

#define VMC(n)  asm volatile("s_waitcnt vmcnt(" #n ")" ::: "memory")
#define BAR()   __builtin_amdgcn_s_barrier()

#define STAGEA(T)                                                                       \
  {                                                                                     \
    const int b_ = (T) & 1;                                                             \
    const int k0_ = (T) * 64;                                                           \
    gload16(Aq + (size_t)(bm + srow) * KP_E + k0_ + sg0 * 16, lds + b_ * 8192 + tid * 16); \
    gload16(Aq + (size_t)(bm + srow + 64) * KP_E + k0_ + sg0 * 16, lds + b_ * 8192 + 4096 + tid * 16); \
  }

#define LOADB(T, BR)                                                                    \
  {                                                                                     \
    const int k0_ = (T) * 64;                                                           \
    BR[0] = *(const i32x4*)(Wq + bo0 + k0_);                                            \
    BR[1] = *(const i32x4*)(Wq + bo1 + k0_);                                            \
    BR[2] = *(const i32x4*)(Wq + bo2 + k0_);                                            \
    BR[3] = *(const i32x4*)(Wq + bo3 + k0_);                                            \
  }

#define COMPUTE12(BB, BR)                                                               \
  {                                                                                     \
    const char* Ab = lds + (BB) * 8192;                                                 \
    i32x4 af[4];                                                                        \
    _Pragma("unroll")                                                                   \
    for (int i_ = 0; i_ < 4; ++i_)                                                      \
      af[i_] = *(const i32x4*)(Ab + (wm * 64 + i_ * 16 + rl) * 64 + sws);               \
    __builtin_amdgcn_s_setprio(1);                                                      \
    _Pragma("unroll")                                                                   \
    for (int i_ = 0; i_ < 4; ++i_)                                                      \
      _Pragma("unroll")                                                                 \
      for (int j_ = 0; j_ < 4; ++j_)                                                    \
        acc[i_][j_] = __builtin_amdgcn_mfma_i32_16x16x64_i8(af[i_], BR[j_],             \
                                                            acc[i_][j_], 0, 0, 0);     \
    __builtin_amdgcn_s_setprio(0);                                                      \
  }

  // prologue: tile 0 (A->LDS, B->bX) in flight
  STAGEA(0)
  LOADB(0, bX)

  for (int tt = 0; tt < 6; ++tt) {            // pairs t = 2tt, 2tt+1 (t = 0..11)
    const int t = tt * 2;
    VMC(0);                                   // A(t) in LDS, B(t) in regs
    BAR();                                    // A(t) visible; prev compute's LDS reads done
    STAGEA(t + 1)
    LOADB(t + 1, bY)
    COMPUTE12(t & 1, bX)
    VMC(0);                                   // A(t+1), B(t+1) landed
    BAR();
    STAGEA(t + 2)                             // t+2 <= 12
    LOADB(t + 2, bX)
    COMPUTE12((t + 1) & 1, bY)
  }
  // tail: tile 12 (buf 0, bX)
  VMC(0);
  BAR();
  COMPUTE12(0, bX)

#undef STAGEA
#undef LOADB
#undef COMPUTE12

  // ===== fused epilogue: dequant + relu -> LDS half-tile -> segmented sum -> agg atomics =====
  BAR();

  u16* tile = (u16*)lds;                        // [128][132] u16
  int* nseg = (int*)(lds + 33792);              // 128 ints
  float* sAl = (float*)(lds + 34304);           // 128 floats
  for (int i = tid; i < 128; i += 256) {
    nseg[i] = nsort[bm + i];
    sAl[i] = sA[bm + i];
  }
  __syncthreads();

  const int rq = (lane >> 4) * 4;
  const int cl = lane & 15;
#pragma unroll
  for (int j = 0; j < 4; ++j) {
    const int col16 = wn * 64 + j * 16 + cl;
    const float swn = sW[bn + col16];
    const float bj = bias[bn + col16];
#pragma unroll
    for (int i = 0; i < 4; ++i) {
      const int r0 = wm * 64 + i * 16 + rq;
#pragma unroll
      for (int q = 0; q < 4; ++q) {
        const int r = r0 + q;
        const float v = fmaf((float)acc[i][j][q], sAl[r] * swn, bj);
        tile[r * 132 + col16] = f2bf(v > 0.f ? v : 0.f);
      }
    }
  }
  __syncthreads();

  const int col = tid & 127;
  const int rbase = (tid >> 7) * 64;
  float s = 0.f;
  int cur = -1;
  for (int r = 0; r < 64; ++r) {
    const int nd = nseg[rbase + r];
    const float v = bf2f(tile[(rbase + r) * 132 + col]);
    if (nd != cur) {
      if (cur >= 0) atomicAdd(&agg[(size_t)cur * D_N + bn + col], s);
      s = 0.f;
      cur = nd;
    }
    if (nd >= 0) s += v;
  }
  if (cur >= 0) atomicAdd(&agg[(size_t)cur * D_N + bn + col], s);

#undef VMC
#undef BAR
}

// ---------------- GIN combine: h = (1+eps)*x + agg -> bf16 (x4 vectorized) ----------------
__global__ void k_build_h(const float* __restrict__ x, const float* __restrict__ agg,
                          const float* __restrict__ epsp, u16* __restrict__ hbf) {
  int i = (blockIdx.x * 256 + threadIdx.x) * 4;
  if (i >= U_N * D_N) return;
  const float ep = 1.f + epsp[0];
  const f32x4 xv = *(const f32x4*)&x[i];
  const f32x4 av = *(const f32x4*)&agg[i];
  u16 r0 = f2bf(ep * xv[0] + av[0]);
  u16 r1 = f2bf(ep * xv[1] + av[1]);
  u16 r2 = f2bf(ep * xv[2] + av[2]);
  u16 r3 = f2bf(ep * xv[3] + av[3]);
  unsigned lo = (unsigned)r0 | ((unsigned)r1 << 16);
  unsigned hi = (unsigned)r2 | ((unsigned)r3 << 16);
  *(uint2*)&hbf[i] = make_uint2(lo, hi);
}

// ------- h1 GEMM: h1b = bf16(hbf @ W1^T), fused BN partial stats -------
__global__ __launch_bounds__(256)
void gemm_h1(const u16* __restrict__ A, const u16* __restrict__ B,
             u16* __restrict__ h1b, float* __restrict__ ssum, float* __restrict__ ssq) {
  __shared__ u16 As[128 * 64];
  __shared__ u16 Bs[128 * 64];
  const int bm = (blockIdx.x / 6) * 128;
  const int bn = (blockIdx.x % 6) * 128;
  const int t = threadIdx.x;
  const int wave = t >> 6, lane = t & 63;
  const int wr = (wave & 1) * 64, wc = (wave >> 1) * 64;
  const int srow = lane >> 3, scol = (lane & 7) * 8;
  const int rl = lane & 15, kl = (lane >> 4) * 8;
  f32x4 acc[4][4] = {};
  for (int k0 = 0; k0 < D_N; k0 += 64) {
#pragma unroll
    for (int q = 0; q < 4; q++) {
      const int c = wave * 4 + q;
      const int row = c * 8 + srow;
      gload16(A + (size_t)(bm + row) * D_N + k0 + scol, As + c * 512);
      gload16(B + (size_t)(bn + row) * D_N + k0 + scol, Bs + c * 512);
    }
    __syncthreads();
#pragma unroll
    for (int ks = 0; ks < 2; ks++) {
      s16x8 af[4], bfr[4];
#pragma unroll
      for (int i = 0; i < 4; i++) af[i] = *(const s16x8*)&As[(wr + i * 16 + rl) * 64 + ks * 32 + kl];
#pragma unroll
      for (int j = 0; j < 4; j++) bfr[j] = *(const s16x8*)&Bs[(wc + j * 16 + rl) * 64 + ks * 32 + kl];
#pragma unroll
      for (int i = 0; i < 4; i++)
#pragma unroll
        for (int j = 0; j < 4; j++)
          acc[i][j] = __builtin_amdgcn_mfma_f32_16x16x32_bf16(af[i], bfr[j], acc[i][j], 0, 0, 0);
    }
    __syncthreads();
  }
  const int cl = lane & 15, rq = (lane >> 4) * 4;
#pragma unroll
  for (int j = 0; j < 4; j++) {
    const int n = bn + wc + j * 16 + cl;
    float cs = 0.f, cq = 0.f;
#pragma unroll
    for (int i = 0; i < 4; i++) {
      const int r = bm + wr + i * 16 + rq;
#pragma unroll
      for (int q = 0; q < 4; q++) {
        const float v = acc[i][j][q];
        cs += v; cq += v * v;
        h1b[(size_t)(r + q) * D_N + n] = f2bf(v);
      }
    }
    cs += __shfl_xor(cs, 16); cq += __shfl_xor(cq, 16);
    cs += __shfl_xor(cs, 32); cq += __shfl_xor(cq, 32);
    if (lane < 16) { atomicAdd(&ssum[n], cs); atomicAdd(&ssq[n], cq); }
  }
}

// ---------------- generic bf16 GEMM, C f32 [M][N], K%64==0 ----------------
__global__ __launch_bounds__(256)
void gemm_bf16_g(const u16* __restrict__ A, const u16* __restrict__ B,
                 float* __restrict__ C, int ntn, int K) {
  __shared__ u16 As[128 * 64];
  __shared__ u16 Bs[128 * 64];
  const int bm = (blockIdx.x / ntn) * 128;
  const int bn = (blockIdx.x % ntn) * 128;
  const int t = threadIdx.x;
  const int wave = t >> 6, lane = t & 63;
  const int wr = (wave & 1) * 64, wc = (wave >> 1) * 64;
  const int srow = lane >> 3, scol = (lane & 7) * 8;
  const int rl = lane & 15, kl = (lane >> 4) * 8;
  const int N = ntn * 128;
  f32x4 acc[4][4] = {};
  for (int k0 = 0; k0 < K; k0 += 64) {
#pragma unroll
    for (int q = 0; q < 4; q++) {
      const int c = wave * 4 + q;
      const int row = c * 8 + srow;
      gload16(A + (size_t)(bm + row) * K + k0 + scol, As + c * 512);
      gload16(B + (size_t)(bn + row) * K + k0 + scol, Bs + c * 512);
    }
    __syncthreads();
#pragma unroll
    for (int ks = 0; ks < 2; ks++) {
      s16x8 af[4], bfr[4];
#pragma unroll
      for (int i = 0; i < 4; i++) af[i] = *(const s16x8*)&As[(wr + i * 16 + rl) * 64 + ks * 32 + kl];
#pragma unroll
      for (int j = 0; j < 4; j++) bfr[j] = *(const s16x8*)&Bs[(wc + j * 16 + rl) * 64 + ks * 32 + kl];
#pragma unroll
      for (int i = 0; i < 4; i++)
#pragma unroll
        for (int j = 0; j < 4; j++)
          acc[i][j] = __builtin_amdgcn_mfma_f32_16x16x32_bf16(af[i], bfr[j], acc[i][j], 0, 0, 0);
    }
    __syncthreads();
  }
  const int cl = lane & 15, rq = (lane >> 4) * 4;
#pragma unroll
  for (int i = 0; i < 4; i++)
#pragma unroll
    for (int j = 0; j < 4; j++) {
      const int n = bn + wc + j * 16 + cl;
      const int r = bm + wr + i * 16 + rq;
#pragma unroll
      for (int q = 0; q < 4; q++)
        C[(size_t)(r + q) * N + n] = acc[i][j][q];
    }
}

// ---------------- BN ----------------
__global__ void k_bnfinal(const float* __restrict__ ssum, const float* __restrict__ ssq,
                          const float* __restrict__ gamma, const float* __restrict__ beta,
                          float* __restrict__ scale, float* __restrict__ shift) {
  int c = blockIdx.x * 256 + threadIdx.x;
  if (c >= D_N) return;
  double mean = (double)ssum[c] / (double)U_N;
  double var = (double)ssq[c] / (double)U_N - mean * mean;
  float sc = (float)((double)gamma[c] / sqrt(var + (double)BN_EPS));
  scale[c] = sc;
  shift[c] = beta[c] - (float)mean * sc;
}

// bnapply x8 vectorized
__global__ void k_bnapply(const u16* __restrict__ h1b, const float* __restrict__ scale,
                          const float* __restrict__ shift, u16* __restrict__ h2) {
  int i = (blockIdx.x * 256 + threadIdx.x) * 8;
  if (i >= U_N * D_N) return;
  const int c = i % D_N;
  const s16x8 hv = *(const s16x8*)&h1b[i];
  s16x8 o;
#pragma unroll
  for (int z = 0; z < 8; z++) {
    const float v = bf2f((u16)hv[z]) * scale[c + z] + shift[c + z];
    o[z] = (short)f2bf(v > 0.f ? v : 0.f);
  }
  *(s16x8*)&h2[i] = o;
}

extern "C" void kernel_launch(void* const* d_in, const int* in_sizes, int n_in,
                              void* d_out, int out_size, void* d_ws, size_t ws_size,
                              hipStream_t stream) {
  const float* x     = (const float*)d_in[0];
  const int*   uniq  = (const int*)d_in[1];
  const int*   srcg  = (const int*)d_in[2];
  const float* tgt   = (const float*)d_in[3];
  const float* edg   = (const float*)d_in[4];
  const float* Wedge = (const float*)d_in[5];
  const float* bedge = (const float*)d_in[6];
  const float* W1    = (const float*)d_in[7];
  const float* W2    = (const float*)d_in[8];
  const float* gamma = (const float*)d_in[9];
  const float* beta  = (const float*)d_in[10];
  const float* epsp  = (const float*)d_in[11];
  float* out = (float*)d_out;
  char* ws = (char*)d_ws;

  char*  Aq    = (char*) (ws + 0);             // 166,453,248 (M_PAD x 832)
  float* agg   = (float*)(ws + 166454272ull);  // 25,165,824
  u16*   h1b   = (u16*)  (ws + 191620096ull);  // 12,582,912
  u16*   hbf   = (u16*)  (ws + 204203008ull);  // 12,582,912
  u16*   h2b   = (u16*)  (ws + 216785920ull);  // 12,582,912
  char*  Wq    = (char*) (ws + 229368832ull);  // 638,976
  u16*   w1b   = (u16*)  (ws + 230007808ull);  // 1,179,648
  u16*   w2b   = (u16*)  (ws + 231187456ull);  // 1,179,648
  float* sA    = (float*)(ws + 232367104ull);  // 800,768
  float* sW    = (float*)(ws + 233167872ull);  // 4,096
  int*   lidx  = (int*)  (ws + 233171968ull);  // 800,000
  int*   eord  = (int*)  (ws + 233971968ull);  // 800,000
  int*   nsort = (int*)  (ws + 234771968ull);  // 800,768
  int*   counts= (int*)  (ws + 235572736ull);  // 32,768
  int*   cursor= (int*)  (ws + 235605504ull);  // 32,768
  int*   starts= (int*)  (ws + 235638272ull);  // 33,024
  float* ssum  = (float*)(ws + 235671296ull);  // 3,072
  float* ssq   = (float*)(ws + 235674368ull);
  float* scale = (float*)(ws + 235677440ull);
  float* shift = (float*)(ws + 235680512ull);

  hipMemsetAsync(counts, 0, 65536, stream);                 // counts + cursor
  hipMemsetAsync(ssum, 0, 2 * D_N * 4, stream);             // ssum + ssq
  hipMemsetAsync(agg, 0, (size_t)U_N * D_N * 4, stream);    // agg zeros
  hipMemsetAsync(nsort + E_N, 0xFF, (M_PAD - E_N) * 4, stream);  // pad rows -> -1

  k_convw_q8<<<D_N / 4, 256, 0, stream>>>(Wedge, Wq, sW);
  k_conv_w2<<<(2 * D_N * D_N + 255) / 256, 256, 0, stream>>>(W1, W2, w1b, w2b);

  k_lh<<<(E_N + 255) / 256, 256, 0, stream>>>(uniq, srcg, lidx, counts);
  k_scan<<<1, 1024, 0, stream>>>(counts, starts);
  k_scatter<<<(E_N + 255) / 256, 256, 0, stream>>>(lidx, starts, cursor, eord, nsort);

  k_pack_q8<<<E_N / 4, 256, 0, stream>>>(tgt, edg, eord, Aq, sA);

  // 1563 M-tiles x 6 N-tiles, 256 threads, ring-2 (A-only LDS), B in registers
  gemm_edge12<<<NMT * 6, 256, 0, stream>>>(Aq, Wq, sA, sW, bedge, nsort, agg);

  k_build_h<<<(U_N * D_N / 4 + 255) / 256, 256, 0, stream>>>(x, agg, epsp, hbf);

  gemm_h1<<<(U_N / 128) * 6, 256, 0, stream>>>(hbf, w1b, h1b, ssum, ssq);

  k_bnfinal<<<3, 256, 0, stream>>>(ssum, ssq, gamma, beta, scale, shift);
  k_bnapply<<<(U_N * D_N / 8 + 255) / 256, 256, 0, stream>>>(h1b, scale, shift, h2b);

  gemm_bf16_g<<<(U_N / 128) * 6, 256, 0, stream>>>(h2b, w2b, out, 6, D_N);
}

// Round 13
// 491.212 us; speedup vs baseline: 1.1122x; 1.1122x over previous
//
#include <hip/hip_runtime.h>
#include <stdint.h>
#include <math.h>

typedef unsigned short u16;
typedef __attribute__((ext_vector_type(4))) float f32x4;
typedef __attribute__((ext_vector_type(8))) short s16x8;
typedef __attribute__((ext_vector_type(4))) int i32x4;

#define U_N 8192
#define E_N 200000
#define M_PAD 200064   // 1563 * 128
#define NMT 1563
#define D_N 768
#define DE_N 50
#define KP_E 832       // 13 * 64
#define NTI 13
#define BN_EPS 1e-5f

__device__ __forceinline__ u16 f2bf(float f) {
  union { float f; unsigned u; } v; v.f = f;
  return (u16)((v.u + 0x7fffu + ((v.u >> 16) & 1u)) >> 16);
}
__device__ __forceinline__ float bf2f(u16 v) {
  union { unsigned u; float f; } x; x.u = ((unsigned)v) << 16; return x.f;
}
__device__ __forceinline__ void gload16(const void* g, void* l) {
  __builtin_amdgcn_global_load_lds((const __attribute__((address_space(1))) void*)g,
                                   (__attribute__((address_space(3))) void*)l, 16, 0, 0);
}

// ---------------- searchsorted + histogram (merged) ----------------
__global__ void k_lh(const int* __restrict__ uniq, const int* __restrict__ src,
                     int* __restrict__ lidx, int* __restrict__ counts) {
  int e = blockIdx.x * 256 + threadIdx.x;
  if (e >= E_N) return;
  int v = src[e];
  int lo = 0, hi = U_N;
  while (lo < hi) { int mid = (lo + hi) >> 1; if (uniq[mid] < v) lo = mid + 1; else hi = mid; }
  lidx[e] = lo;
  atomicAdd(&counts[lo], 1);
}

__global__ void k_scan(const int* __restrict__ counts, int* __restrict__ starts) {
  __shared__ int part[1024];
  const int t = threadIdx.x;
  const int base = t * 8;
  int loc[8]; int s = 0;
#pragma unroll
  for (int i = 0; i < 8; i++) { loc[i] = s; s += counts[base + i]; }
  part[t] = s; __syncthreads();
  for (int off = 1; off < 1024; off <<= 1) {
    int v = (t >= off) ? part[t - off] : 0;
    __syncthreads();
    part[t] += v;
    __syncthreads();
  }
  const int pre = (t == 0) ? 0 : part[t - 1];
#pragma unroll
  for (int i = 0; i < 8; i++) starts[base + i] = pre + loc[i];
  if (t == 1023) starts[8192] = pre + s;
}

__global__ void k_scatter(const int* __restrict__ lidx, const int* __restrict__ starts,
                          int* __restrict__ cursor, int* __restrict__ eord,
                          int* __restrict__ nsort) {
  int e = blockIdx.x * 256 + threadIdx.x;
  if (e >= E_N) return;
  int u = lidx[e];
  int pos = atomicAdd(&cursor[u], 1);
  eord[starts[u] + pos] = e;
  nsort[starts[u] + pos] = u;
}

// ------- pack+quantize A (sorted order): Aq[pos][k] int8 (K=832), per-row amax -------
__global__ __launch_bounds__(256)
void k_pack_q8(const float* __restrict__ tgt, const float* __restrict__ edg,
               const int* __restrict__ eord, char* __restrict__ Aq,
               float* __restrict__ sA) {
  const int row = blockIdx.x * 4 + (threadIdx.x >> 6);
  const int lane = threadIdx.x & 63;
  if (row >= E_N) return;
  const int e = eord[row];
  const int k0 = lane * 16;
  float v[16];
#pragma unroll
  for (int z = 0; z < 16; z++) v[z] = 0.f;
  if (k0 < D_N) {
    const f32x4* p = (const f32x4*)(tgt + (size_t)e * D_N + k0);
#pragma unroll
    for (int zz = 0; zz < 4; zz++) {
      const f32x4 f = p[zz];
#pragma unroll
      for (int b = 0; b < 4; b++) v[zz * 4 + b] = f[b];
    }
  } else if (k0 < KP_E) {
#pragma unroll
    for (int z = 0; z < 16; z++) {
      const int kk = k0 + z - D_N;
      v[z] = (kk < DE_N) ? edg[(size_t)e * DE_N + kk] : 0.f;
    }
  }
  float am = 0.f;
#pragma unroll
  for (int z = 0; z < 16; z++) am = fmaxf(am, fabsf(v[z]));
#pragma unroll
  for (int off = 32; off > 0; off >>= 1) am = fmaxf(am, __shfl_xor(am, off));
  am = fmaxf(am, 1e-8f);
  const float inv = 127.f / am;
  if (lane == 0) sA[row] = am / 127.f;
  if (k0 < KP_E) {
    int wq[4];
#pragma unroll
    for (int zz = 0; zz < 4; zz++) {
      int b0 = (int)rintf(fminf(fmaxf(v[zz*4+0] * inv, -127.f), 127.f));
      int b1 = (int)rintf(fminf(fmaxf(v[zz*4+1] * inv, -127.f), 127.f));
      int b2 = (int)rintf(fminf(fmaxf(v[zz*4+2] * inv, -127.f), 127.f));
      int b3 = (int)rintf(fminf(fmaxf(v[zz*4+3] * inv, -127.f), 127.f));
      wq[zz] = (b0 & 255) | ((b1 & 255) << 8) | ((b2 & 255) << 16) | (b3 << 24);
    }
    i32x4 out = {wq[0], wq[1], wq[2], wq[3]};
    *(i32x4*)(Aq + (size_t)row * KP_E + k0) = out;
  }
}

// ------- quantize W_edge rows (818 -> 832 pad), per-row amax -------
__global__ __launch_bounds__(256)
void k_convw_q8(const float* __restrict__ W, char* __restrict__ Wq,
                float* __restrict__ sW) {
  const int row = blockIdx.x * 4 + (threadIdx.x >> 6);
  const int lane = threadIdx.x & 63;
  if (row >= D_N) return;
  const int k0 = lane * 16;
  float v[16];
#pragma unroll
  for (int z = 0; z < 16; z++) v[z] = 0.f;
  if (k0 < KP_E) {
#pragma unroll
    for (int z = 0; z < 16; z++) {
      const int kk = k0 + z;
      v[z] = (kk < D_N + DE_N) ? W[(size_t)row * (D_N + DE_N) + kk] : 0.f;
    }
  }
  float am = 0.f;
#pragma unroll
  for (int z = 0; z < 16; z++) am = fmaxf(am, fabsf(v[z]));
#pragma unroll
  for (int off = 32; off > 0; off >>= 1) am = fmaxf(am, __shfl_xor(am, off));
  am = fmaxf(am, 1e-8f);
  const float inv = 127.f / am;
  if (lane == 0) sW[row] = am / 127.f;
  if (k0 < KP_E) {
    int wq[4];
#pragma unroll
    for (int zz = 0; zz < 4; zz++) {
      int b0 = (int)rintf(fminf(fmaxf(v[zz*4+0] * inv, -127.f), 127.f));
      int b1 = (int)rintf(fminf(fmaxf(v[zz*4+1] * inv, -127.f), 127.f));
      int b2 = (int)rintf(fminf(fmaxf(v[zz*4+2] * inv, -127.f), 127.f));
      int b3 = (int)rintf(fminf(fmaxf(v[zz*4+3] * inv, -127.f), 127.f));
      wq[zz] = (b0 & 255) | ((b1 & 255) << 8) | ((b2 & 255) << 16) | (b3 << 24);
    }
    i32x4 out = {wq[0], wq[1], wq[2], wq[3]};
    *(i32x4*)(Wq + (size_t)row * KP_E + k0) = out;
  }
}

// ---------------- merged bf16 weight conversion (W1 + W2) ----------------
__global__ void k_conv_w2(const float* __restrict__ W1, const float* __restrict__ W2,
                          u16* __restrict__ w1b, u16* __restrict__ w2b) {
  int i = blockIdx.x * 256 + threadIdx.x;
  const int C = D_N * D_N;
  if (i < C) w1b[i] = f2bf(W1[i]);
  else if (i < 2 * C) w2b[i - C] = f2bf(W2[i - C]);
}

// ====== edge GEMM (FINAL = round-9 proven best): int8, 128x128, 4 waves, ring-2 BK=64,
// 4 blocks/CU, 2 barriers/iter, fused dequant+segment-sum epilogue ======
// Swizzle (proven, 0 conflicts): LDS slot p of row r holds global slot p ^ ((r>>1)&3).
__global__ __launch_bounds__(256, 4)
void gemm_edge9(const char* __restrict__ Aq, const char* __restrict__ Wq,
                const float* __restrict__ sA, const float* __restrict__ sW,
                const float* __restrict__ bias, const int* __restrict__ nsort,
                float* __restrict__ agg) {
  // ring buf b at b*16384: A [128][64B] at +0, B [128][64B] at +8192.
  // epilogue: u16 tile[128][132] at 0 (33792 B); nseg at 33792; sAl at 34304.
  __shared__ char lds[34816];

  // bijective XCD swizzle, nwg = 9378 = 8*1172 + 2
  const int orig = blockIdx.x;
  const int xcd = orig & 7, i8_ = orig >> 3;
  const int wgid = (xcd < 2 ? xcd * 1173 : 2346 + (xcd - 2) * 1172) + i8_;
  const int bm = (wgid / 6) * 128;
  const int bn = (wgid % 6) * 128;

  const int tid = threadIdx.x;
  const int w = tid >> 6, lane = tid & 63;
  const int wm = w & 1, wn = w >> 1;          // wave tile: rows wm*64, cols wn*64
  const int rl = lane & 15, K16 = lane >> 4;
  const int sws = (K16 ^ ((rl >> 1) & 3)) * 16;
  const int srow = tid >> 2;
  const int sg0 = (tid & 3) ^ ((srow >> 1) & 3);

  i32x4 acc[4][4] = {};

#define VMC(n)  asm volatile("s_waitcnt vmcnt(" #n ")" ::: "memory")
#define BAR()   __builtin_amdgcn_s_barrier()

#define STAGE9(T)                                                                       \
  {                                                                                     \
    const int b_ = (T) & 1;                                                             \
    const int k0_ = (T) * 64;                                                           \
    gload16(Aq + (size_t)(bm + srow) * KP_E + k0_ + sg0 * 16, lds + b_ * 16384 + tid * 16); \
    gload16(Aq + (size_t)(bm + srow + 64) * KP_E + k0_ + sg0 * 16, lds + b_ * 16384 + 4096 + tid * 16); \
    gload16(Wq + (size_t)(bn + srow) * KP_E + k0_ + sg0 * 16, lds + b_ * 16384 + 8192 + tid * 16); \
    gload16(Wq + (size_t)(bn + srow + 64) * KP_E + k0_ + sg0 * 16, lds + b_ * 16384 + 12288 + tid * 16); \
  }

#define COMPUTE9(BB)                                                                    \
  {                                                                                     \
    const char* Ab = lds + (BB) * 16384;                                                \
    const char* Bb = Ab + 8192;                                                         \
    i32x4 af[4], bfr[4];                                                                \
    _Pragma("unroll")                                                                   \
    for (int j_ = 0; j_ < 4; ++j_)                                                      \
      bfr[j_] = *(const i32x4*)(Bb + (wn * 64 + j_ * 16 + rl) * 64 + sws);              \
    _Pragma("unroll")                                                                   \
    for (int i_ = 0; i_ < 4; ++i_)                                                      \
      af[i_] = *(const i32x4*)(Ab + (wm * 64 + i_ * 16 + rl) * 64 + sws);               \
    __builtin_amdgcn_s_setprio(1);                                                      \
    _Pragma("unroll")                                                                   \
    for (int i_ = 0; i_ < 4; ++i_)                                                      \
      _Pragma("unroll")                                                                 \
      for (int j_ = 0; j_ < 4; ++j_)                                                    \
        acc[i_][j_] = __builtin_amdgcn_mfma_i32_16x16x64_i8(af[i_], bfr[j_],            \
                                                            acc[i_][j_], 0, 0, 0);     \
    __builtin_amdgcn_s_setprio(0);                                                      \
  }

  STAGE9(0)
  for (int t = 0; t < NTI - 1; ++t) {         // t = 0..11
    BAR();                                    // compute(t-1) done before overwriting its buf
    STAGE9(t + 1)
    VMC(4);                                   // tile t landed (t+1's 4 loads outstanding)
    BAR();
    asm volatile("" ::: "memory");
    COMPUTE9(t & 1)
  }
  BAR();
  VMC(0);
  BAR();
  asm volatile("" ::: "memory");
  COMPUTE9(0)                                 // t = 12 -> buf 0

#undef STAGE9
#undef COMPUTE9

  // ===== fused epilogue: dequant + relu -> LDS half-tile -> segmented sum -> agg atomics =====
  BAR();

  u16* tile = (u16*)lds;                        // [128][132] u16
  int* nseg = (int*)(lds + 33792);              // 128 ints
  float* sAl = (float*)(lds + 34304);           // 128 floats
  for (int i = tid; i < 128; i += 256) {
    nseg[i] = nsort[bm + i];
    sAl[i] = sA[bm + i];
  }
  __syncthreads();

  const int rq = (lane >> 4) * 4;
  const int cl = lane & 15;
#pragma unroll
  for (int j = 0; j < 4; ++j) {
    const int col16 = wn * 64 + j * 16 + cl;
    const float swn = sW[bn + col16];
    const float bj = bias[bn + col16];
#pragma unroll
    for (int i = 0; i < 4; ++i) {
      const int r0 = wm * 64 + i * 16 + rq;
#pragma unroll
      for (int q = 0; q < 4; ++q) {
        const int r = r0 + q;
        const float v = fmaf((float)acc[i][j][q], sAl[r] * swn, bj);
        tile[r * 132 + col16] = f2bf(v > 0.f ? v : 0.f);
      }
    }
  }
  __syncthreads();

  const int col = tid & 127;
  const int rbase = (tid >> 7) * 64;
  float s = 0.f;
  int cur = -1;
  for (int r = 0; r < 64; ++r) {
    const int nd = nseg[rbase + r];
    const float v = bf2f(tile[(rbase + r) * 132 + col]);
    if (nd != cur) {
      if (cur >= 0) atomicAdd(&agg[(size_t)cur * D_N + bn + col], s);
      s = 0.f;
      cur = nd;
    }
    if (nd >= 0) s += v;
  }
  if (cur >= 0) atomicAdd(&agg[(size_t)cur * D_N + bn + col], s);

#undef VMC
#undef BAR
}

// ---------------- GIN combine: h = (1+eps)*x + agg -> bf16 (x4 vectorized) ----------------
__global__ void k_build_h(const float* __restrict__ x, const float* __restrict__ agg,
                          const float* __restrict__ epsp, u16* __restrict__ hbf) {
  int i = (blockIdx.x * 256 + threadIdx.x) * 4;
  if (i >= U_N * D_N) return;
  const float ep = 1.f + epsp[0];
  const f32x4 xv = *(const f32x4*)&x[i];
  const f32x4 av = *(const f32x4*)&agg[i];
  u16 r0 = f2bf(ep * xv[0] + av[0]);
  u16 r1 = f2bf(ep * xv[1] + av[1]);
  u16 r2 = f2bf(ep * xv[2] + av[2]);
  u16 r3 = f2bf(ep * xv[3] + av[3]);
  unsigned lo = (unsigned)r0 | ((unsigned)r1 << 16);
  unsigned hi = (unsigned)r2 | ((unsigned)r3 << 16);
  *(uint2*)&hbf[i] = make_uint2(lo, hi);
}

// ------- h1 GEMM: h1b = bf16(hbf @ W1^T), fused BN partial stats -------
__global__ __launch_bounds__(256)
void gemm_h1(const u16* __restrict__ A, const u16* __restrict__ B,
             u16* __restrict__ h1b, float* __restrict__ ssum, float* __restrict__ ssq) {
  __shared__ u16 As[128 * 64];
  __shared__ u16 Bs[128 * 64];
  const int bm = (blockIdx.x / 6) * 128;
  const int bn = (blockIdx.x % 6) * 128;
  const int t = threadIdx.x;
  const int wave = t >> 6, lane = t & 63;
  const int wr = (wave & 1) * 64, wc = (wave >> 1) * 64;
  const int srow = lane >> 3, scol = (lane & 7) * 8;
  const int rl = lane & 15, kl = (lane >> 4) * 8;
  f32x4 acc[4][4] = {};
  for (int k0 = 0; k0 < D_N; k0 += 64) {
#pragma unroll
    for (int q = 0; q < 4; q++) {
      const int c = wave * 4 + q;
      const int row = c * 8 + srow;
      gload16(A + (size_t)(bm + row) * D_N + k0 + scol, As + c * 512);
      gload16(B + (size_t)(bn + row) * D_N + k0 + scol, Bs + c * 512);
    }
    __syncthreads();
#pragma unroll
    for (int ks = 0; ks < 2; ks++) {
      s16x8 af[4], bfr[4];
#pragma unroll
      for (int i = 0; i < 4; i++) af[i] = *(const s16x8*)&As[(wr + i * 16 + rl) * 64 + ks * 32 + kl];
#pragma unroll
      for (int j = 0; j < 4; j++) bfr[j] = *(const s16x8*)&Bs[(wc + j * 16 + rl) * 64 + ks * 32 + kl];
#pragma unroll
      for (int i = 0; i < 4; i++)
#pragma unroll
        for (int j = 0; j < 4; j++)
          acc[i][j] = __builtin_amdgcn_mfma_f32_16x16x32_bf16(af[i], bfr[j], acc[i][j], 0, 0, 0);
    }
    __syncthreads();
  }
  const int cl = lane & 15, rq = (lane >> 4) * 4;
#pragma unroll
  for (int j = 0; j < 4; j++) {
    const int n = bn + wc + j * 16 + cl;
    float cs = 0.f, cq = 0.f;
#pragma unroll
    for (int i = 0; i < 4; i++) {
      const int r = bm + wr + i * 16 + rq;
#pragma unroll
      for (int q = 0; q < 4; q++) {
        const float v = acc[i][j][q];
        cs += v; cq += v * v;
        h1b[(size_t)(r + q) * D_N + n] = f2bf(v);
      }
    }
    cs += __shfl_xor(cs, 16); cq += __shfl_xor(cq, 16);
    cs += __shfl_xor(cs, 32); cq += __shfl_xor(cq, 32);
    if (lane < 16) { atomicAdd(&ssum[n], cs); atomicAdd(&ssq[n], cq); }
  }
}

// ---------------- generic bf16 GEMM, C f32 [M][N], K%64==0 ----------------
__global__ __launch_bounds__(256)
void gemm_bf16_g(const u16* __restrict__ A, const u16* __restrict__ B,
                 float* __restrict__ C, int ntn, int K) {
  __shared__ u16 As[128 * 64];
  __shared__ u16 Bs[128 * 64];
  const int bm = (blockIdx.x / ntn) * 128;
  const int bn = (blockIdx.x % ntn) * 128;
  const int t = threadIdx.x;
  const int wave = t >> 6, lane = t & 63;
  const int wr = (wave & 1) * 64, wc = (wave >> 1) * 64;
  const int srow = lane >> 3, scol = (lane & 7) * 8;
  const int rl = lane & 15, kl = (lane >> 4) * 8;
  const int N = ntn * 128;
  f32x4 acc[4][4] = {};
  for (int k0 = 0; k0 < K; k0 += 64) {
#pragma unroll
    for (int q = 0; q < 4; q++) {
      const int c = wave * 4 + q;
      const int row = c * 8 + srow;
      gload16(A + (size_t)(bm + row) * K + k0 + scol, As + c * 512);
      gload16(B + (size_t)(bn + row) * K + k0 + scol, Bs + c * 512);
    }
    __syncthreads();
#pragma unroll
    for (int ks = 0; ks < 2; ks++) {
      s16x8 af[4], bfr[4];
#pragma unroll
      for (int i = 0; i < 4; i++) af[i] = *(const s16x8*)&As[(wr + i * 16 + rl) * 64 + ks * 32 + kl];
#pragma unroll
      for (int j = 0; j < 4; j++) bfr[j] = *(const s16x8*)&Bs[(wc + j * 16 + rl) * 64 + ks * 32 + kl];
#pragma unroll
      for (int i = 0; i < 4; i++)
#pragma unroll
        for (int j = 0; j < 4; j++)
          acc[i][j] = __builtin_amdgcn_mfma_f32_16x16x32_bf16(af[i], bfr[j], acc[i][j], 0, 0, 0);
    }
    __syncthreads();
  }
  const int cl = lane & 15, rq = (lane >> 4) * 4;
#pragma unroll
  for (int i = 0; i < 4; i++)
#pragma unroll
    for (int j = 0; j < 4; j++) {
      const int n = bn + wc + j * 16 + cl;
      const int r = bm + wr + i * 16 + rq;
#pragma unroll
      for (int q = 0; q < 4; q++)
        C[(size_t)(r + q) * N + n] = acc[i][j][q];
    }
}

// ---------------- BN ----------------
__global__ void k_bnfinal(const float* __restrict__ ssum, const float* __restrict__ ssq,
                          const float* __restrict__ gamma, const float* __restrict__ beta,
                          float* __restrict__ scale, float* __restrict__ shift) {
  int c = blockIdx.x * 256 + threadIdx.x;
  if (c >= D_N) return;
  double mean = (double)ssum[c] / (double)U_N;
  double var = (double)ssq[c] / (double)U_N - mean * mean;
  float sc = (float)((double)gamma[c] / sqrt(var + (double)BN_EPS));
  scale[c] = sc;
  shift[c] = beta[c] - (float)mean * sc;
}

// bnapply x8 vectorized
__global__ void k_bnapply(const u16* __restrict__ h1b, const float* __restrict__ scale,
                          const float* __restrict__ shift, u16* __restrict__ h2) {
  int i = (blockIdx.x * 256 + threadIdx.x) * 8;
  if (i >= U_N * D_N) return;
  const int c = i % D_N;
  const s16x8 hv = *(const s16x8*)&h1b[i];
  s16x8 o;
#pragma unroll
  for (int z = 0; z < 8; z++) {
    const float v = bf2f((u16)hv[z]) * scale[c + z] + shift[c + z];
    o[z] = (short)f2bf(v > 0.f ? v : 0.f);
  }
  *(s16x8*)&h2[i] = o;
}

extern "C" void kernel_launch(void* const* d_in, const int* in_sizes, int n_in,
                              void* d_out, int out_size, void* d_ws, size_t ws_size,
                              hipStream_t stream) {
  const float* x     = (const float*)d_in[0];
  const int*   uniq  = (const int*)d_in[1];
  const int*   srcg  = (const int*)d_in[2];
  const float* tgt   = (const float*)d_in[3];
  const float* edg   = (const float*)d_in[4];
  const float* Wedge = (const float*)d_in[5];
  const float* bedge = (const float*)d_in[6];
  const float* W1    = (const float*)d_in[7];
  const float* W2    = (const float*)d_in[8];
  const float* gamma = (const float*)d_in[9];
  const float* beta  = (const float*)d_in[10];
  const float* epsp  = (const float*)d_in[11];
  float* out = (float*)d_out;
  char* ws = (char*)d_ws;

  char*  Aq    = (char*) (ws + 0);             // 166,453,248 (M_PAD x 832)
  float* agg   = (float*)(ws + 166454272ull);  // 25,165,824
  u16*   h1b   = (u16*)  (ws + 191620096ull);  // 12,582,912
  u16*   hbf   = (u16*)  (ws + 204203008ull);  // 12,582,912
  u16*   h2b   = (u16*)  (ws + 216785920ull);  // 12,582,912
  char*  Wq    = (char*) (ws + 229368832ull);  // 638,976
  u16*   w1b   = (u16*)  (ws + 230007808ull);  // 1,179,648
  u16*   w2b   = (u16*)  (ws + 231187456ull);  // 1,179,648
  float* sA    = (float*)(ws + 232367104ull);  // 800,768
  float* sW    = (float*)(ws + 233167872ull);  // 4,096
  int*   lidx  = (int*)  (ws + 233171968ull);  // 800,000
  int*   eord  = (int*)  (ws + 233971968ull);  // 800,000
  int*   nsort = (int*)  (ws + 234771968ull);  // 800,768
  int*   counts= (int*)  (ws + 235572736ull);  // 32,768
  int*   cursor= (int*)  (ws + 235605504ull);  // 32,768
  int*   starts= (int*)  (ws + 235638272ull);  // 33,024
  float* ssum  = (float*)(ws + 235671296ull);  // 3,072
  float* ssq   = (float*)(ws + 235674368ull);
  float* scale = (float*)(ws + 235677440ull);
  float* shift = (float*)(ws + 235680512ull);

  hipMemsetAsync(counts, 0, 65536, stream);                 // counts + cursor
  hipMemsetAsync(ssum, 0, 2 * D_N * 4, stream);             // ssum + ssq
  hipMemsetAsync(agg, 0, (size_t)U_N * D_N * 4, stream);    // agg zeros
  hipMemsetAsync(nsort + E_N, 0xFF, (M_PAD - E_N) * 4, stream);  // pad rows -> -1

  k_convw_q8<<<D_N / 4, 256, 0, stream>>>(Wedge, Wq, sW);
  k_conv_w2<<<(2 * D_N * D_N + 255) / 256, 256, 0, stream>>>(W1, W2, w1b, w2b);

  k_lh<<<(E_N + 255) / 256, 256, 0, stream>>>(uniq, srcg, lidx, counts);
  k_scan<<<1, 1024, 0, stream>>>(counts, starts);
  k_scatter<<<(E_N + 255) / 256, 256, 0, stream>>>(lidx, starts, cursor, eord, nsort);

  k_pack_q8<<<E_N / 4, 256, 0, stream>>>(tgt, edg, eord, Aq, sA);

  // 1563 M-tiles x 6 N-tiles, 256 threads, ring-2, 4 blocks/CU (proven best config)
  gemm_edge9<<<NMT * 6, 256, 0, stream>>>(Aq, Wq, sA, sW, bedge, nsort, agg);

  k_build_h<<<(U_N * D_N / 4 + 255) / 256, 256, 0, stream>>>(x, agg, epsp, hbf);

  gemm_h1<<<(U_N / 128) * 6, 256, 0, stream>>>(hbf, w1b, h1b, ssum, ssq);

  k_bnfinal<<<3, 256, 0, stream>>>(ssum, ssq, gamma, beta, scale, shift);
  k_bnapply<<<(U_N * D_N / 8 + 255) / 256, 256, 0, stream>>>(h1b, scale, shift, h2b);

  gemm_bf16_g<<<(U_N / 128) * 6, 256, 0, stream>>>(h2b, w2b, out, 6, D_N);
}